// Round 1
// 1102.714 us; speedup vs baseline: 1.2899x; 1.2899x over previous
//
#include <hip/hip_runtime.h>
#include <float.h>
#include <math.h>

#define NTOK 16384
#define KCB  2048
#define DDIM 256
#define NCB  10
// Screening margin. Screen is a SINGLE bf16 MFMA pass now: dist error rms
// ~2.9e-5 (dominated by bf16 rounding of res and E; Hoeffding tail with
// realized per-term bounds makes 1e-3 a >20-sigma guarantee). Candidates
// within margin are exact-evaluated with the bit-identical np FMA chain.
#define MARGIN 1.0e-3f

typedef __attribute__((ext_vector_type(8))) short  short8;
typedef __attribute__((ext_vector_type(4))) float  f32x4;

static __device__ __forceinline__ unsigned short f2bf(float f) {
    unsigned int b = __float_as_uint(f);
    unsigned int r = b + 0x7FFFu + ((b >> 16) & 1u);   // RNE
    return (unsigned short)(r >> 16);
}
static __device__ __forceinline__ float bf2f(unsigned short h) {
    return __uint_as_float((unsigned int)h << 16);
}

// ---- np-bit-exact pairwise sum of squares (rows of 256): E rows + z rows ----
__global__ __launch_bounds__(256) void norms_all_kernel(const float* __restrict__ E,
                                                        const float* __restrict__ z,
                                                        float* __restrict__ sseE,
                                                        float* __restrict__ normA) {
    const int gw   = (blockIdx.x * 256 + threadIdx.x) >> 6;
    const int lane = threadIdx.x & 63;
    const int row  = gw * 4 + (lane >> 4);
    const int l    = lane & 15;
    const float* src = nullptr; float* dst = nullptr;
    if (row < NCB * KCB)             { src = E + (size_t)row * DDIM;               dst = sseE + row; }
    else if (row < NCB * KCB + NTOK) { src = z + (size_t)(row - NCB * KCB) * DDIM; dst = normA + (row - NCB * KCB); }
    float r = 0.f;
    if (src) {
        const float* a = src + ((l >> 3) << 7) + (l & 7);
        float v = a[0];
        r = __fmul_rn(v, v);
        #pragma unroll
        for (int k = 1; k < 16; ++k) { v = a[k * 8]; r = __fadd_rn(r, __fmul_rn(v, v)); }
    }
    r = __fadd_rn(r, __shfl_xor(r, 1, 64));
    r = __fadd_rn(r, __shfl_xor(r, 2, 64));
    r = __fadd_rn(r, __shfl_xor(r, 4, 64));
    r = __fadd_rn(r, __shfl_xor(r, 8, 64));
    if (src && l == 0) *dst = r;
}

// ---- convert: E -> Eh bf16; z -> resH; W1/W2 -> transposed bf16 ----
// (lo halves dropped: screen is single-pass bf16 now)
__global__ __launch_bounds__(256) void conv_all_kernel(const float* __restrict__ E,
                                                       const float* __restrict__ z,
                                                       const float* __restrict__ W1,
                                                       const float* __restrict__ W2,
                                                       unsigned short* __restrict__ Eh,
                                                       unsigned short* __restrict__ resH,
                                                       unsigned short* __restrict__ w1t,
                                                       unsigned short* __restrict__ w2t) {
    int i = blockIdx.x * 256 + threadIdx.x;
    if (i < 5242880) {
        Eh[i] = f2bf(E[i]);
    } else if (i < 9437184) {
        int j = i - 5242880;
        resH[j] = f2bf(z[j]);
    } else if (i < 9502720) {
        int j = i - 9437184;
        int n = j >> 8, k = j & 255;
        w1t[j] = f2bf(W1[k * 256 + n]);
    } else {
        int j = i - 9502720;
        int n = j >> 8, k = j & 255;
        w2t[j] = f2bf(W2[k * 1024 + n]);
    }
}

// ---- MFMA screening: 128 tokens x 128 codes per block; SINGLE bf16 pass ----
// Outputs per (token,slice): slice min of approx dist (gMin), candidate slots
// within MARGIN, count. Exactness restored downstream by candidate exact-eval.
__global__ __launch_bounds__(256) void vq_screen(const unsigned short* __restrict__ resH,
                                                 const unsigned short* __restrict__ Ehi,
                                                 const float* __restrict__ sseEi,
                                                 int2* __restrict__ gSlots,
                                                 int* __restrict__ gCnt,
                                                 float* __restrict__ gMin) {
    __shared__ unsigned short sAh[128 * 40];
    __shared__ unsigned short sBh[128 * 40];
    __shared__ float sC[128];
    __shared__ int   lCnt[128];
    __shared__ int2  lSlot[128][4];
    const int tid = threadIdx.x;
    const int wv = tid >> 6, lane = tid & 63;
    const int l15 = lane & 15, qd = lane >> 4;
    const int tile = blockIdx.x >> 4, slice = blockIdx.x & 15;
    const int t0 = tile * 128, c0 = slice * 128;

    if (tid < 128) { lCnt[tid] = 0; sC[tid] = sseEi[c0 + tid]; }
    {
        int2 inf; inf.x = 0x7F800000; inf.y = 0;
        ((int2*)lSlot)[tid] = inf; ((int2*)lSlot)[tid + 256] = inf;
    }

    f32x4 acc[2][8];
    #pragma unroll
    for (int m = 0; m < 2; ++m)
        #pragma unroll
        for (int n = 0; n < 8; ++n) acc[m][n] = (f32x4){0.f, 0.f, 0.f, 0.f};

    const int r0 = tid >> 2, cc4 = tid & 3;
    const int r1 = (tid + 256) >> 2;
    for (int kc = 0; kc < 8; ++kc) {
        const int db = kc * 32;
        __syncthreads();
        *(uint4*)(sAh + r0 * 40 + cc4 * 8) = *(const uint4*)(resH + (size_t)(t0 + r0) * 256 + db + cc4 * 8);
        *(uint4*)(sAh + r1 * 40 + cc4 * 8) = *(const uint4*)(resH + (size_t)(t0 + r1) * 256 + db + cc4 * 8);
        *(uint4*)(sBh + r0 * 40 + cc4 * 8) = *(const uint4*)(Ehi  + (size_t)(c0 + r0) * 256 + db + cc4 * 8);
        *(uint4*)(sBh + r1 * 40 + cc4 * 8) = *(const uint4*)(Ehi  + (size_t)(c0 + r1) * 256 + db + cc4 * 8);
        __syncthreads();

        short8 ah[2];
        #pragma unroll
        for (int m = 0; m < 2; ++m)
            ah[m] = *(const short8*)(sAh + (wv * 32 + m * 16 + l15) * 40 + qd * 8);
        #pragma unroll
        for (int n = 0; n < 8; ++n) {
            short8 bh = *(const short8*)(sBh + (n * 16 + l15) * 40 + qd * 8);
            #pragma unroll
            for (int m = 0; m < 2; ++m)
                acc[m][n] = __builtin_amdgcn_mfma_f32_16x16x32_bf16(ah[m], bh, acc[m][n], 0, 0, 0);
        }
    }

    #pragma unroll
    for (int m = 0; m < 2; ++m)
        #pragma unroll
        for (int n = 0; n < 8; ++n) {
            float Cv = sC[n * 16 + l15];
            #pragma unroll
            for (int r = 0; r < 4; ++r) acc[m][n][r] = fmaf(-2.f, acc[m][n][r], Cv);
        }
    #pragma unroll
    for (int m = 0; m < 2; ++m)
        #pragma unroll
        for (int r = 0; r < 4; ++r) {
            float v = acc[m][0][r];
            #pragma unroll
            for (int n = 1; n < 8; ++n) v = fminf(v, acc[m][n][r]);
            v = fminf(v, __shfl_xor(v, 1, 64));
            v = fminf(v, __shfl_xor(v, 2, 64));
            v = fminf(v, __shfl_xor(v, 4, 64));
            v = fminf(v, __shfl_xor(v, 8, 64));
            int tloc = wv * 32 + m * 16 + qd * 4 + r;
            if (l15 == 0) gMin[(t0 + tloc) * 16 + slice] = v;   // slice min (approx)
            float thr = v + MARGIN;
            #pragma unroll
            for (int n = 0; n < 8; ++n) {
                float sv = acc[m][n][r];
                if (sv <= thr) {
                    int pos = atomicAdd(&lCnt[tloc], 1);
                    if (pos < 4) {
                        int2 e; e.x = __float_as_int(sv); e.y = c0 + n * 16 + l15;
                        lSlot[tloc][pos] = e;
                    }
                }
            }
        }
    __syncthreads();
    {
        int tloc = tid >> 1, half = tid & 1;
        size_t base = (size_t)(t0 + tloc) * 64 + slice * 4 + half * 2;
        gSlots[base]     = lSlot[tloc][half * 2];
        gSlots[base + 1] = lSlot[tloc][half * 2 + 1];
        if (!half) gCnt[(t0 + tloc) * 16 + slice] = lCnt[tloc];
    }
}

// ---- exact np chain (per-lane, row from LDS copy of res) ----
static __device__ __forceinline__ float np_chain(const float* __restrict__ sRow,
                                                 const float* __restrict__ Ei,
                                                 int cc, float A, float C) {
    const float4* e = (const float4*)(Ei + (size_t)cc * DDIM);
    float a = 0.f;
    #pragma unroll 8
    for (int k = 0; k < 64; ++k) {
        float4 ev = e[k];
        const float4 rv = *(const float4*)(sRow + k * 4);
        a = fmaf(rv.x, ev.x, a); a = fmaf(rv.y, ev.y, a);
        a = fmaf(rv.z, ev.z, a); a = fmaf(rv.w, ev.w, a);
    }
    return __fadd_rn(fmaf(-2.f, a, A), C);
}

// ---- finalize: 1024 blocks x 4 waves x 4 tokens/wave ----
__global__ __launch_bounds__(256) void vq_post(const float* __restrict__ resSrc,
                                               const float* __restrict__ Ei,
                                               const float* __restrict__ sseEi,
                                               float* __restrict__ res,
                                               float* __restrict__ zq,
                                               float* __restrict__ codes,
                                               float* __restrict__ lossPart,
                                               float* __restrict__ normA,
                                               unsigned short* __restrict__ resHp,
                                               unsigned short* __restrict__ zqb,
                                               const int2* __restrict__ gSlots,
                                               const int* __restrict__ gCnt,
                                               const float* __restrict__ gMin,
                                               int iter) {
    __shared__ float sScr[4][4][256];
    const int tid = threadIdx.x;
    const int wv = tid >> 6, lane = tid & 63;
    const int g = lane >> 4, l15 = lane & 15;
    const int tb = blockIdx.x * 16 + wv * 4;
    float lsum = 0.f;

    // phase 1: all independent loads
    int2 sl[4]; float4 r4[4]; int cnt4[4]; float smin4[4]; float4 zq4[4]; float A4[4];
    #pragma unroll
    for (int j = 0; j < 4; ++j) sl[j] = gSlots[(size_t)(tb + j) * 64 + lane];
    #pragma unroll
    for (int j = 0; j < 4; ++j)
        r4[j] = *(const float4*)(resSrc + (size_t)(tb + j) * DDIM + lane * 4);
    #pragma unroll
    for (int j = 0; j < 4; ++j) cnt4[j]  = (lane < 16) ? gCnt[(tb + j) * 16 + lane] : 0;
    #pragma unroll
    for (int j = 0; j < 4; ++j) smin4[j] = (lane < 16) ? gMin[(tb + j) * 16 + lane] : FLT_MAX;
    #pragma unroll
    for (int j = 0; j < 4; ++j) A4[j] = normA[tb + j];
    if (iter > 0) {
        #pragma unroll
        for (int j = 0; j < 4; ++j)
            zq4[j] = *(const float4*)(zq + (size_t)(tb + j) * DDIM + lane * 4);
    }

    // phase 2: winners
    int winner[4];
    #pragma unroll
    for (int j = 0; j < 4; ++j) {
        float gm = smin4[j];
        #pragma unroll
        for (int o = 32; o >= 1; o >>= 1) gm = fminf(gm, __shfl_xor(gm, o, 64));
        const float thr = gm + MARGIN;
        float sv = __int_as_float(sl[j].x);
        unsigned long long bal = __ballot((sv <= thr) ? 1 : 0);
        bool ovfRel = __any((lane < 16 && cnt4[j] > 4 && smin4[j] <= thr) ? 1 : 0);
        if (!ovfRel && __popcll(bal) == 1) {
            winner[j] = __shfl(sl[j].y, __ffsll(bal) - 1, 64);
        } else if (!ovfRel) {
            // lane-parallel exact eval: each lane evaluates its OWN slot's
            // candidate via the bit-identical np FMA chain; non-candidates
            // evaluate row 0 (broadcast, cheap) and discard.
            *(float4*)(&sScr[wv][j][lane * 4]) = r4[j];
            const bool qal = (sv <= thr);
            const int cc = qal ? sl[j].y : 0;
            float s = np_chain(sScr[wv][j], Ei, cc, A4[j], sseEi[cc]);
            unsigned long long best = qal
                ? (((unsigned long long)__float_as_uint(s) << 32) | (unsigned)cc)
                : ~0ULL;
            #pragma unroll
            for (int o = 32; o >= 1; o >>= 1) {
                unsigned long long ot = __shfl_xor(best, o, 64);
                if (ot < best) best = ot;
            }
            winner[j] = (int)(unsigned)(best & 0xFFFFFFFFu);
        } else {
            // rare: full exact rescan
            *(float4*)(&sScr[wv][j][lane * 4]) = r4[j];
            unsigned long long best = ~0ULL;
            for (int cc = lane; cc < KCB; cc += 64) {
                float s = np_chain(sScr[wv][j], Ei, cc, A4[j], sseEi[cc]);
                unsigned long long key =
                    ((unsigned long long)__float_as_uint(s) << 32) | (unsigned)cc;
                if (key < best) best = key;
            }
            #pragma unroll
            for (int o = 32; o >= 1; o >>= 1) {
                unsigned long long ot = __shfl_xor(best, o, 64);
                if (ot < best) best = ot;
            }
            winner[j] = (int)(unsigned)(best & 0xFFFFFFFFu);
        }
    }
    #pragma unroll
    for (int j = 0; j < 4; ++j)
        if (lane == j) codes[(size_t)(tb + j) * NCB + iter] = (float)winner[j];

    // phase 3: concurrent gathers
    float4 q4[4];
    #pragma unroll
    for (int j = 0; j < 4; ++j)
        q4[j] = *(const float4*)(Ei + (size_t)winner[j] * DDIM + lane * 4);

    // phase 4: exact chain update + stores
    #pragma unroll
    for (int j = 0; j < 4; ++j) {
        const size_t go = (size_t)(tb + j) * DDIM + lane * 4;
        float4 rn4, zqi4;
        float tqx = q4[j].x - r4[j].x; zqi4.x = r4[j].x + tqx; rn4.x = r4[j].x - zqi4.x;
        float tqy = q4[j].y - r4[j].y; zqi4.y = r4[j].y + tqy; rn4.y = r4[j].y - zqi4.y;
        float tqz = q4[j].z - r4[j].z; zqi4.z = r4[j].z + tqz; rn4.z = r4[j].z - zqi4.z;
        float tqw = q4[j].w - r4[j].w; zqi4.w = r4[j].w + tqw; rn4.w = r4[j].w - zqi4.w;
        lsum = fmaf(tqx, tqx, lsum); lsum = fmaf(tqy, tqy, lsum);
        lsum = fmaf(tqz, tqz, lsum); lsum = fmaf(tqw, tqw, lsum);
        *(float4*)(res + go) = rn4;
        {
            unsigned short h[4] = { f2bf(rn4.x), f2bf(rn4.y), f2bf(rn4.z), f2bf(rn4.w) };
            *(ushort4*)(resHp + go) = *(ushort4*)h;
        }
        if (iter == 0) {
            *(float4*)(zq + go) = zqi4;
            unsigned short u[4] = { f2bf(zqi4.x), f2bf(zqi4.y), f2bf(zqi4.z), f2bf(zqi4.w) };
            *(ushort4*)(zqb + go) = *(ushort4*)u;
        } else {
            zq4[j].x += zqi4.x; zq4[j].y += zqi4.y;
            zq4[j].z += zqi4.z; zq4[j].w += zqi4.w;
            *(float4*)(zq + go) = zq4[j];
        }
        *(float4*)(&sScr[wv][j][lane * 4]) = rn4;
    }
    // phase 5: np-exact norms, 4 tokens in parallel (16-lane group g -> token tb+g)
    {
        const float* a = &sScr[wv][g][((l15 >> 3) << 7) + (l15 & 7)];
        float v = a[0];
        float r = __fmul_rn(v, v);
        #pragma unroll
        for (int k = 1; k < 16; ++k) { v = a[k * 8]; r = __fadd_rn(r, __fmul_rn(v, v)); }
        r = __fadd_rn(r, __shfl_xor(r, 1, 64));
        r = __fadd_rn(r, __shfl_xor(r, 2, 64));
        r = __fadd_rn(r, __shfl_xor(r, 4, 64));
        r = __fadd_rn(r, __shfl_xor(r, 8, 64));
        if (l15 == 0) normA[tb + g] = r;
    }
    #pragma unroll
    for (int o = 32; o >= 1; o >>= 1) lsum += __shfl_xor(lsum, o, 64);
    if (lane == 0) lossPart[iter * 4096 + blockIdx.x * 4 + wv] = lsum;
}

// ---- vq loss finalize (10 iters x 4096 wave partials) ----
__global__ __launch_bounds__(256) void loss_final(const float* __restrict__ lossPart,
                                                  float* __restrict__ vql) {
    __shared__ float sRed[4];
    float s = 0.f;
    for (int i = threadIdx.x; i < 40960; i += 256) s += lossPart[i];
    #pragma unroll
    for (int o = 32; o >= 1; o >>= 1) s += __shfl_xor(s, o, 64);
    if ((threadIdx.x & 63) == 0) sRed[threadIdx.x >> 6] = s;
    __syncthreads();
    if (threadIdx.x == 0)
        vql[0] = (sRed[0] + sRed[1] + sRed[2] + sRed[3]) * (1.25f / 4194304.f);
}

// ---- semantic head, bf16 MFMA ----
__global__ __launch_bounds__(256) void semantic_mfma(const unsigned short* __restrict__ zqb,
                                                     const float* __restrict__ tgt,
                                                     const unsigned short* __restrict__ w1t,
                                                     const float* __restrict__ b1,
                                                     const unsigned short* __restrict__ w2t,
                                                     const float* __restrict__ b2,
                                                     float* __restrict__ semLoss) {
    __shared__ unsigned short sZ[32 * 264];
    __shared__ unsigned short sH[32 * 264];
    __shared__ float sRed[4];
    const int tid = threadIdx.x;
    const int wv = tid >> 6, lane = tid & 63;
    const int l15 = lane & 15, qd = lane >> 4;
    const int tb = blockIdx.x * 32;

    {
        int row = tid >> 3, seg = tid & 7;
        const uint4* src = (const uint4*)(zqb + (size_t)(tb + row) * 256);
        uint4* dst = (uint4*)(&sZ[row * 264]);
        #pragma unroll
        for (int p = 0; p < 4; ++p) dst[seg * 4 + p] = src[seg * 4 + p];
    }
    __syncthreads();

    short8 az[8][2];
    #pragma unroll
    for (int kc = 0; kc < 8; ++kc)
        #pragma unroll
        for (int m = 0; m < 2; ++m)
            az[kc][m] = *(const short8*)(&sZ[(16 * m + l15) * 264 + kc * 32 + qd * 8]);

    #pragma unroll
    for (int nt4 = 0; nt4 < 4; ++nt4) {
        const int nt = wv * 4 + nt4;
        f32x4 acc0 = {0.f,0.f,0.f,0.f}, acc1 = {0.f,0.f,0.f,0.f};
        const unsigned short* bb = w1t + (size_t)(16 * nt + l15) * 256 + qd * 8;
        #pragma unroll
        for (int kc = 0; kc < 8; ++kc) {
            short8 b = *(const short8*)(bb + kc * 32);
            acc0 = __builtin_amdgcn_mfma_f32_16x16x32_bf16(az[kc][0], b, acc0, 0, 0, 0);
            acc1 = __builtin_amdgcn_mfma_f32_16x16x32_bf16(az[kc][1], b, acc1, 0, 0, 0);
        }
        const float b1v = b1[16 * nt + l15];
        #pragma unroll
        for (int r = 0; r < 4; ++r) {
            float x0 = acc0[r] + b1v;
            float x1 = acc1[r] + b1v;
            sH[(4 * qd + r) * 264 + 16 * nt + l15]      = f2bf(0.5f * x0 * (1.f + erff(x0 * 0.70710678f)));
            sH[(16 + 4 * qd + r) * 264 + 16 * nt + l15] = f2bf(0.5f * x1 * (1.f + erff(x1 * 0.70710678f)));
        }
    }
    __syncthreads();

    short8 ah[8][2];
    #pragma unroll
    for (int kc = 0; kc < 8; ++kc)
        #pragma unroll
        for (int m = 0; m < 2; ++m)
            ah[kc][m] = *(const short8*)(&sH[(16 * m + l15) * 264 + kc * 32 + qd * 8]);

    float lsum = 0.f;
    for (int t = 0; t < 16; ++t) {
        const int nt = wv * 16 + t;
        f32x4 acc0 = {0.f,0.f,0.f,0.f}, acc1 = {0.f,0.f,0.f,0.f};
        const unsigned short* bb = w2t + (size_t)(16 * nt + l15) * 256 + qd * 8;
        #pragma unroll
        for (int kc = 0; kc < 8; ++kc) {
            short8 b = *(const short8*)(bb + kc * 32);
            acc0 = __builtin_amdgcn_mfma_f32_16x16x32_bf16(ah[kc][0], b, acc0, 0, 0, 0);
            acc1 = __builtin_amdgcn_mfma_f32_16x16x32_bf16(ah[kc][1], b, acc1, 0, 0, 0);
        }
        const int n = 16 * nt + l15;
        const float b2v = b2[n];
        #pragma unroll
        for (int r = 0; r < 4; ++r) {
            float dv0 = (acc0[r] + b2v) - tgt[(size_t)(tb + 4 * qd + r) * 1024 + n];
            float dv1 = (acc1[r] + b2v) - tgt[(size_t)(tb + 16 + 4 * qd + r) * 1024 + n];
            lsum = fmaf(dv0, dv0, lsum);
            lsum = fmaf(dv1, dv1, lsum);
        }
    }
    #pragma unroll
    for (int o = 32; o >= 1; o >>= 1) lsum += __shfl_xor(lsum, o, 64);
    if (lane == 0) sRed[wv] = lsum;
    __syncthreads();
    if (tid == 0)
        atomicAdd(semLoss, (sRed[0] + sRed[1] + sRed[2] + sRed[3]) * (1.0f / 16777216.f));
}

extern "C" void kernel_launch(void* const* d_in, const int* in_sizes, int n_in,
                              void* d_out, int out_size, void* d_ws, size_t ws_size,
                              hipStream_t stream) {
    const float* z   = (const float*)d_in[0];
    const float* tgt = (const float*)d_in[1];
    const float* E   = (const float*)d_in[2];
    const float* W1  = (const float*)d_in[3];
    const float* b1  = (const float*)d_in[4];
    const float* W2  = (const float*)d_in[5];
    const float* b2  = (const float*)d_in[6];

    float* out   = (float*)d_out;
    float* zq    = out;
    float* codes = out + (size_t)NTOK * DDIM;
    float* vql   = codes + (size_t)NTOK * NCB;       // [vq_loss, semantic_loss]

    char* w = (char*)d_ws;
    float*          res   = (float*)(w);                         // 16 MiB
    unsigned short* resH  = (unsigned short*)(w + 16777216);     // 8 MiB
    unsigned short* Eh    = (unsigned short*)(w + 33554432);     // 10 MiB
    unsigned short* zqb   = (unsigned short*)(w + 54525952);     // 8 MiB
    int2*           gSlots= (int2*)(w + 62914560);               // 8 MiB
    int*            gCnt  = (int*)(w + 71303168);                // 1 MiB
    float*          gMin  = (float*)(w + 72351744);              // 1 MiB
    float*          sseE  = (float*)(w + 73400320);              // 80 KiB (pad 128K)
    float*          normA = (float*)(w + 73531392);              // 64 KiB (pad 128K)
    float*          lossPart=(float*)(w + 73662464);             // 160 KiB (pad 256K)
    unsigned short* w1t   = (unsigned short*)(w + 73924608);     // 128 KiB
    unsigned short* w2t   = (unsigned short*)(w + 74055680);     // 512 KiB

    hipMemsetAsync(vql, 0, 2 * sizeof(float), stream);
    norms_all_kernel<<<9216, 256, 0, stream>>>(E, z, sseE, normA);
    conv_all_kernel<<<38144, 256, 0, stream>>>(E, z, W1, W2, Eh, resH, w1t, w2t);
    for (int it = 0; it < NCB; ++it) {
        const float*          Ei    = E  + (size_t)it * KCB * DDIM;
        const unsigned short* Ehi   = Eh + (size_t)it * KCB * DDIM;
        const float*          sseEi = sseE + (size_t)it * KCB;
        const float* resSrc = (it == 0) ? z : res;
        vq_screen<<<2048, 256, 0, stream>>>(resH, Ehi, sseEi, gSlots, gCnt, gMin);
        vq_post<<<1024, 256, 0, stream>>>(resSrc, Ei, sseEi, res, zq, codes, lossPart,
                                          normA, resH, zqb, gSlots, gCnt, gMin, it);
        if (it == 0)
            semantic_mfma<<<512, 256, 0, stream>>>(zqb, tgt, w1t, b1, w2t, b2, vql + 1);
    }
    loss_final<<<1, 256, 0, stream>>>(lossPart, vql);
}